// Round 1
// 753.672 us; speedup vs baseline: 1.2304x; 1.2304x over previous
//
#include <hip/hip_runtime.h>

// ---------------------------------------------------------------------------
// SlidingAttention: B=8 S=4096 E=1024 H=8 W=128 D=128, window look-around 1.
// fp32 inputs/outputs (per reference); bf16 intermediates in ws, fp32 accum.
// Pipeline:
//   proj_kernel x3 : q/k/v = x @ W^T per head  -> ws as [B,H,S,D] bf16
//   attn_kernel    : per (b,h,window) tile, full 384-key row in regs,
//                    O^T orientation; O overwrites q region in-place [B,H,S,D]
//   cvt_wo         : Wo fp32 -> bf16 once (into dead k-plane of ws)
//   outproj_kernel : out = O @ Wo^T + bo  (m97 structure: global_load_lds +
//                    XOR-swizzled LDS, BK=64)      -> [B,S,E] fp32
// ws layout: q/O (64MiB) | k then Wo_bf16 (64MiB) | v (64MiB) = 192 MiB
// ---------------------------------------------------------------------------

typedef __attribute__((ext_vector_type(8))) short short8;
typedef __attribute__((ext_vector_type(4))) short short4v;
typedef __attribute__((ext_vector_type(4))) float float4v;

#define MFMA16(a, b, c) __builtin_amdgcn_mfma_f32_16x16x32_bf16((a), (b), (c), 0, 0, 0)

constexpr int NW_ = 32;    // windows per sequence
constexpr int LD_ = 136;   // padded LDS row stride (bf16 elems): 272B, 16B-aligned

__device__ __forceinline__ unsigned short f2bf(float f) {
  unsigned u = __builtin_bit_cast(unsigned, f);
  u += 0x7fffu + ((u >> 16) & 1u);          // RNE
  return (unsigned short)(u >> 16);
}

// pack 8 fp32 -> 8 bf16
__device__ __forceinline__ short8 pack8(float4v a0, float4v a1) {
  short8 s;
  for (int j = 0; j < 4; ++j) { s[j] = (short)f2bf(a0[j]); s[4 + j] = (short)f2bf(a1[j]); }
  return s;
}

// async global->LDS, 16B per lane; LDS dest = wave-uniform base + lane*16
__device__ __forceinline__ void gload16(const unsigned short* g, unsigned short* l) {
  __builtin_amdgcn_global_load_lds(
      (const __attribute__((address_space(1))) unsigned int*)g,
      (__attribute__((address_space(3))) unsigned int*)l, 16, 0, 0);
}

// ---------------------------------------------------------------------------
// Per-head projection: rows r=(b,s,h) are flat-contiguous in x (r*128+d).
// out[(b*8+h)*4096 + s][o]  ([B,H,S,D] bf16).  M=262144, N=K=128.
// ---------------------------------------------------------------------------
__global__ __launch_bounds__(256) void proj_kernel(
    const float* __restrict__ x, const float* __restrict__ w,
    unsigned short* __restrict__ out) {
  __shared__ unsigned short lA[128 * LD_];
  __shared__ unsigned short lB[128 * LD_];
  const int tid = threadIdx.x;
  const long m0 = (long)blockIdx.x * 128;

  for (int idx = tid; idx < 2048; idx += 256) {   // A tile: 128x128 fp32 -> bf16
    const float* src = x + m0 * 128 + (long)idx * 8;
    float4v a0 = *(const float4v*)(src);
    float4v a1 = *(const float4v*)(src + 4);
    *(short8*)&lA[(idx >> 4) * LD_ + (idx & 15) * 8] = pack8(a0, a1);
  }
  for (int idx = tid; idx < 2048; idx += 256) {   // W tile [n][k] (= B^T, NT layout)
    const float* src = w + idx * 8;
    float4v a0 = *(const float4v*)(src);
    float4v a1 = *(const float4v*)(src + 4);
    *(short8*)&lB[(idx >> 4) * LD_ + (idx & 15) * 8] = pack8(a0, a1);
  }
  __syncthreads();

  const int wv = tid >> 6, L = tid & 63, lr = L & 15, lg = L >> 4;
  const int wm = wv >> 1, wn = wv & 1;   // wave -> 64x64 quadrant
  float4v acc[4][4];
  for (int a = 0; a < 4; ++a)
    for (int b = 0; b < 4; ++b)
      for (int r = 0; r < 4; ++r) acc[a][b][r] = 0.f;

  for (int ks = 0; ks < 4; ++ks) {
    short8 af[4], bf[4];
    for (int mt = 0; mt < 4; ++mt)
      af[mt] = *(const short8*)&lA[(wm * 64 + mt * 16 + lr) * LD_ + ks * 32 + lg * 8];
    for (int nt = 0; nt < 4; ++nt)
      bf[nt] = *(const short8*)&lB[(wn * 64 + nt * 16 + lr) * LD_ + ks * 32 + lg * 8];
    for (int mt = 0; mt < 4; ++mt)
      for (int nt = 0; nt < 4; ++nt)
        acc[mt][nt] = MFMA16(af[mt], bf[nt], acc[mt][nt]);
  }
  __syncthreads();
  for (int mt = 0; mt < 4; ++mt)          // stage C (bf16) back into lA
    for (int nt = 0; nt < 4; ++nt)
      for (int r = 0; r < 4; ++r)
        lA[(wm * 64 + mt * 16 + lg * 4 + r) * LD_ + wn * 64 + nt * 16 + lr] =
            f2bf(acc[mt][nt][r]);
  __syncthreads();
  for (int idx = tid; idx < 2048; idx += 256) {   // coalesced permuted store
    int r = idx >> 4, c = idx & 15;
    long row = m0 + r;                             // row = (b*S+s)*H + h
    int b = (int)(row >> 15), s = (int)((row >> 3) & 4095), h = (int)(row & 7);
    long g = ((long)(b * 8 + h) * 4096 + s) * 128 + c * 8;
    *(short8*)(out + g) = *(const short8*)&lA[r * LD_ + c * 8];
  }
}

// ---------------------------------------------------------------------------
// Attention: block = (b,h,window i), 512 threads = 8 waves, wave w owns
// 16 q-rows sq in [w*16, w*16+16).  S^T = K·Q^T per chunk (lane owns column
// sq = w*16 + (lane&15); column spread over 4 quads -> shfl_xor 16/32).
// O^T = V^T·P^T so both PV operands are contiguous LDS reads and the global
// store packs 4 consecutive d.  O overwrites qp in place.
// ---------------------------------------------------------------------------
__global__ __launch_bounds__(512, 2) void attn_kernel(
    const unsigned short* __restrict__ qp, const unsigned short* __restrict__ kp,
    const unsigned short* __restrict__ vp, unsigned short* __restrict__ op) {
  __shared__ unsigned short lQ[128 * LD_];
  __shared__ unsigned short lK[128 * LD_];   // K chunks, then reused for P
  __shared__ unsigned short lV[128 * LD_];   // V^T chunk
  const int tid = threadIdx.x;
  const int bid = blockIdx.x;
  const int b = bid >> 8, h = (bid >> 5) & 7, i = bid & 31;
  const long base = (long)(b * 8 + h) * (4096L * 128);

  for (int idx = tid; idx < 2048; idx += 512)
    *(short8*)&lQ[(idx >> 4) * LD_ + (idx & 15) * 8] =
        *(const short8*)(qp + base + (long)i * 16384 + (long)idx * 8);

  const int wv = tid >> 6, L = tid & 63, lr = L & 15, lg = L >> 4;
  const bool valid[3] = {i > 0, true, i < NW_ - 1};
  float4v Sacc[3][8];

  // ---- phase 1: S^T chunks (full 384-key row kept in registers) ----
  for (int j = 0; j < 3; ++j) {
    if (!valid[j]) continue;               // block-uniform
    const int jw = i - 1 + j;
    __syncthreads();                       // lQ staged / prev chunk's lK reads done
    for (int idx = tid; idx < 2048; idx += 512)
      *(short8*)&lK[(idx >> 4) * LD_ + (idx & 15) * 8] =
          *(const short8*)(kp + base + (long)jw * 16384 + (long)idx * 8);
    __syncthreads();
    for (int mt = 0; mt < 8; ++mt)
      for (int r = 0; r < 4; ++r) Sacc[j][mt][r] = 0.f;
    for (int ks = 0; ks < 4; ++ks) {
      short8 bq = *(const short8*)&lQ[(wv * 16 + lr) * LD_ + ks * 32 + lg * 8];
      for (int mt = 0; mt < 8; ++mt) {
        short8 ak = *(const short8*)&lK[(mt * 16 + lr) * LD_ + ks * 32 + lg * 8];
        Sacc[j][mt] = MFMA16(ak, bq, Sacc[j][mt]);
      }
    }
  }

  // ---- softmax stats (column sq spread over 4 quads) ----
  float mraw = -3.0e38f;
  for (int j = 0; j < 3; ++j) {
    if (!valid[j]) continue;
    for (int mt = 0; mt < 8; ++mt)
      for (int r = 0; r < 4; ++r) mraw = fmaxf(mraw, Sacc[j][mt][r]);
  }
  mraw = fmaxf(mraw, __shfl_xor(mraw, 16));
  mraw = fmaxf(mraw, __shfl_xor(mraw, 32));
  const float csc = 0.08838834764831845f * 1.4426950408889634f;  // scale*log2(e)
  const float mm = mraw * csc;
  float lsum = 0.f;
  float4v Oacc[8];
  for (int mt = 0; mt < 8; ++mt)
    for (int r = 0; r < 4; ++r) Oacc[mt][r] = 0.f;

  // ---- phase 2: P write + V^T load + PV per chunk ----
  for (int j = 0; j < 3; ++j) {
    if (!valid[j]) continue;
    const int jw = i - 1 + j;
    __syncthreads();                       // prev lK/lV consumers done
    for (int mt = 0; mt < 8; ++mt) {       // P: 4 consecutive sk per lane -> b64
      short4v pk;
      for (int r = 0; r < 4; ++r) {
        float p = exp2f(Sacc[j][mt][r] * csc - mm);
        lsum += p;
        pk[r] = (short)f2bf(p);
      }
      *(short4v*)&lK[(wv * 16 + lr) * LD_ + mt * 16 + lg * 4] = pk;
    }
    for (int idx = tid; idx < 1024; idx += 512) {   // V -> V^T (paired b32 writes)
      int pr = idx & 63, c = idx >> 6;
      const unsigned short* src = vp + base + (long)jw * 16384 + (long)(2 * pr) * 128 + c * 8;
      short8 v0 = *(const short8*)(src);
      short8 v1 = *(const short8*)(src + 128);
      for (int jj = 0; jj < 8; ++jj) {
        unsigned val = ((unsigned)(unsigned short)v0[jj]) |
                       (((unsigned)(unsigned short)v1[jj]) << 16);
        *(unsigned*)&lV[(c * 8 + jj) * LD_ + 2 * pr] = val;
      }
    }
    __syncthreads();
    for (int ks = 0; ks < 4; ++ks) {
      short8 bp = *(const short8*)&lK[(wv * 16 + lr) * LD_ + ks * 32 + lg * 8];
      for (int mt = 0; mt < 8; ++mt) {
        short8 av = *(const short8*)&lV[(mt * 16 + lr) * LD_ + ks * 32 + lg * 8];
        Oacc[mt] = MFMA16(av, bp, Oacc[mt]);
      }
    }
  }

  lsum += __shfl_xor(lsum, 16);
  lsum += __shfl_xor(lsum, 32);
  const float rl = 1.f / lsum;
  const long obase = base + (long)i * 16384;
  for (int mt = 0; mt < 8; ++mt) {         // O^T: 4 consecutive d per lane -> b64 store
    short4v ok;
    for (int r = 0; r < 4; ++r) ok[r] = (short)f2bf(Oacc[mt][r] * rl);
    *(short4v*)(op + obase + (long)(wv * 16 + lr) * 128 + mt * 16 + lg * 4) = ok;
  }
}

// ---------------------------------------------------------------------------
// Wo fp32 [1024][1024] -> bf16 once (k-plane of ws is dead after attn).
// ---------------------------------------------------------------------------
__global__ __launch_bounds__(256) void cvt_wo(
    const float* __restrict__ w, unsigned short* __restrict__ o) {
  long idx = (long)blockIdx.x * 256 + threadIdx.x;   // 8 elems per thread
  const float* src = w + idx * 8;
  float4v a0 = *(const float4v*)(src);
  float4v a1 = *(const float4v*)(src + 4);
  *(short8*)(o + idx * 8) = pack8(a0, a1);
}

// ---------------------------------------------------------------------------
// out[b*S+s][e] = sum_{h,d} O[b,h,s,d] * Wob[e][h*128+d] + bo[e]   (fp32 out)
// M=32768, N=K=1024; 128x128 tile, BK=64, m97 structure:
//   global_load_lds 16B (linear LDS dest) + inverse-XOR-swizzled global src
//   + XOR-swizzled ds_read_b128 (rule #21: both-sides-or-neither).
// Swizzle: granule g' = g ^ (row&7) within each 128B row (8 granules of 16B)
// -> fragment reads bank-balanced (2 lanes / 16B slot) despite 128B stride.
// ---------------------------------------------------------------------------
__global__ __launch_bounds__(256) void outproj_kernel(
    const unsigned short* __restrict__ O, const unsigned short* __restrict__ Wob,
    const float* __restrict__ bo, float* __restrict__ out) {
  __shared__ unsigned short lA[128 * 64];   // 16 KiB, linear (gload_lds dest)
  __shared__ unsigned short lB[128 * 64];
  const int tid = threadIdx.x;
  const long m0 = (long)blockIdx.x * 128;
  const int n0 = blockIdx.y * 128;
  const int wv = tid >> 6, L = tid & 63, lr = L & 15, lg = L >> 4;
  const int wm = wv >> 1, wn = wv & 1;

  // staging geometry: lane L covers row r_t = wv*32 + t*8 + (L>>3), granule L&7.
  // Slot (r,g) must hold global granule g ^ (r&7); (r&7) == (L>>3)&7 for all t.
  const int rsub = L >> 3;                  // 0..7
  const int xg = ((L & 7) ^ rsub) * 8;      // pre-swizzled source column (elems)

  const int bb = (int)(m0 >> 12);           // batch (uniform per block)
  const int sbase = (int)(m0 & 4095);
  long Abase[4], Bbase[4];                  // per-lane, hoisted out of K-loop
#pragma unroll
  for (int t = 0; t < 4; ++t) {
    int r = wv * 32 + t * 8 + rsub;
    Abase[t] = (long)bb * 4194304 + (long)(sbase + r) * 128 + xg;  // h=0,d0=0
    Bbase[t] = (long)(n0 + r) * 1024 + xg;
  }

  float4v acc[4][4];
  for (int a = 0; a < 4; ++a)
    for (int b = 0; b < 4; ++b)
      for (int r = 0; r < 4; ++r) acc[a][b][r] = 0.f;

  for (int kk = 0; kk < 1024; kk += 64) {
    const long aoff = ((long)(kk >> 7) << 19) + (kk & 64);  // head stride 2^19
    __syncthreads();                        // previous compute done
#pragma unroll
    for (int t = 0; t < 4; ++t) {
      gload16(O + Abase[t] + aoff, &lA[(wv * 32 + t * 8) * 64]);
      gload16(Wob + Bbase[t] + kk, &lB[(wv * 32 + t * 8) * 64]);
    }
    __syncthreads();                        // vmcnt drained by barrier semantics
#pragma unroll
    for (int ks = 0; ks < 2; ++ks) {
      short8 af[4], bw[4];
      const int gsw = ((ks * 4 + lg) ^ (lr & 7)) << 3;   // swizzled read column
#pragma unroll
      for (int mt = 0; mt < 4; ++mt)
        af[mt] = *(const short8*)&lA[(wm * 64 + mt * 16 + lr) * 64 + gsw];
#pragma unroll
      for (int nt = 0; nt < 4; ++nt)
        bw[nt] = *(const short8*)&lB[(wn * 64 + nt * 16 + lr) * 64 + gsw];
#pragma unroll
      for (int mt = 0; mt < 4; ++mt)
#pragma unroll
        for (int nt = 0; nt < 4; ++nt)
          acc[mt][nt] = MFMA16(af[mt], bw[nt], acc[mt][nt]);
    }
  }

  // direct fp32 stores in C-layout: each quad stores 16 consecutive dwords (64B)
  for (int nt = 0; nt < 4; ++nt) {
    float bv = bo[n0 + wn * 64 + nt * 16 + lr];
    for (int mt = 0; mt < 4; ++mt)
      for (int r = 0; r < 4; ++r)
        out[(m0 + wm * 64 + mt * 16 + lg * 4 + r) * 1024 + n0 + wn * 64 + nt * 16 + lr] =
            acc[mt][nt][r] + bv;
  }
}

// ---------------------------------------------------------------------------
extern "C" void kernel_launch(void* const* d_in, const int* in_sizes, int n_in,
                              void* d_out, int out_size, void* d_ws, size_t ws_size,
                              hipStream_t stream) {
  const float* values = (const float*)d_in[0];
  const float* keys   = (const float*)d_in[1];
  const float* query  = (const float*)d_in[2];
  const float* Wv     = (const float*)d_in[3];
  const float* Wk     = (const float*)d_in[4];
  const float* Wq     = (const float*)d_in[5];
  const float* Wo     = (const float*)d_in[6];
  const float* bo     = (const float*)d_in[7];
  float* out = (float*)d_out;

  const size_t plane = 8UL * 8 * 4096 * 128;      // B*H*S*D = 33554432 elems
  unsigned short* qp = (unsigned short*)d_ws;
  unsigned short* kp = qp + plane;
  unsigned short* vp = kp + plane;

  proj_kernel<<<2048, 256, 0, stream>>>(query, Wq, qp);
  proj_kernel<<<2048, 256, 0, stream>>>(keys, Wk, kp);
  proj_kernel<<<2048, 256, 0, stream>>>(values, Wv, vp);
  attn_kernel<<<2048, 512, 0, stream>>>(qp, kp, vp, qp);     // O overwrites q region
  cvt_wo<<<512, 256, 0, stream>>>(Wo, kp);                   // k-plane dead after attn
  outproj_kernel<<<dim3(256, 8), 256, 0, stream>>>(qp, kp, bo, out);
}

// Round 3
// 685.110 us; speedup vs baseline: 1.3535x; 1.1001x over previous
//
#include <hip/hip_runtime.h>

// ---------------------------------------------------------------------------
// SlidingAttention: B=8 S=4096 E=1024 H=8 W=128 D=128, window look-around 1.
// fp32 inputs/outputs (per reference); bf16 intermediates in ws, fp32 accum.
// Pipeline:
//   proj_kernel x3 : q/k/v = x @ W^T per head  -> ws as [B,H,S,D] bf16
//   attn_kernel    : per (b,h,window), online softmax over 64-row K/V chunks,
//                    dbuf K prefetch via global_load_lds, P in regs via shfl,
//                    O^T orientation; O overwrites q region in-place
//   cvt_wo         : Wo fp32 -> bf16 once (into dead k-plane of ws)
//   outproj_kernel : out = O @ Wo^T + bo  (m97 structure)   -> [B,S,E] fp32
// ws layout: q/O (64MiB) | k then Wo_bf16 (64MiB) | v (64MiB) = 192 MiB
// ---------------------------------------------------------------------------

typedef __attribute__((ext_vector_type(8))) short short8;
typedef __attribute__((ext_vector_type(4))) short short4v;
typedef __attribute__((ext_vector_type(4))) float float4v;
typedef __attribute__((ext_vector_type(4))) unsigned int uint4v;

#define MFMA16(a, b, c) __builtin_amdgcn_mfma_f32_16x16x32_bf16((a), (b), (c), 0, 0, 0)

constexpr int NW_ = 32;    // windows per sequence
constexpr int LD_ = 136;   // padded LDS row stride for proj kernel

__device__ __forceinline__ unsigned short f2bf(float f) {
  unsigned u = __builtin_bit_cast(unsigned, f);
  u += 0x7fffu + ((u >> 16) & 1u);          // RNE
  return (unsigned short)(u >> 16);
}

__device__ __forceinline__ short8 pack8(float4v a0, float4v a1) {
  short8 s;
  for (int j = 0; j < 4; ++j) { s[j] = (short)f2bf(a0[j]); s[4 + j] = (short)f2bf(a1[j]); }
  return s;
}

// async global->LDS, 16B per lane; LDS dest = wave-uniform base + lane*16
__device__ __forceinline__ void gload16(const unsigned short* g, unsigned short* l) {
  __builtin_amdgcn_global_load_lds(
      (const __attribute__((address_space(1))) unsigned int*)g,
      (__attribute__((address_space(3))) unsigned int*)l, 16, 0, 0);
}

// ---------------------------------------------------------------------------
// Per-head projection: rows r=(b,s,h) are flat-contiguous in x (r*128+d).
// out[(b*8+h)*4096 + s][o]  ([B,H,S,D] bf16).  M=262144, N=K=128.
// ---------------------------------------------------------------------------
__global__ __launch_bounds__(256) void proj_kernel(
    const float* __restrict__ x, const float* __restrict__ w,
    unsigned short* __restrict__ out) {
  __shared__ unsigned short lA[128 * LD_];
  __shared__ unsigned short lB[128 * LD_];
  const int tid = threadIdx.x;
  const long m0 = (long)blockIdx.x * 128;

  for (int idx = tid; idx < 2048; idx += 256) {   // A tile: 128x128 fp32 -> bf16
    const float* src = x + m0 * 128 + (long)idx * 8;
    float4v a0 = *(const float4v*)(src);
    float4v a1 = *(const float4v*)(src + 4);
    *(short8*)&lA[(idx >> 4) * LD_ + (idx & 15) * 8] = pack8(a0, a1);
  }
  for (int idx = tid; idx < 2048; idx += 256) {   // W tile [n][k] (= B^T, NT layout)
    const float* src = w + idx * 8;
    float4v a0 = *(const float4v*)(src);
    float4v a1 = *(const float4v*)(src + 4);
    *(short8*)&lB[(idx >> 4) * LD_ + (idx & 15) * 8] = pack8(a0, a1);
  }
  __syncthreads();

  const int wv = tid >> 6, L = tid & 63, lr = L & 15, lg = L >> 4;
  const int wm = wv >> 1, wn = wv & 1;   // wave -> 64x64 quadrant
  float4v acc[4][4];
  for (int a = 0; a < 4; ++a)
    for (int b = 0; b < 4; ++b)
      for (int r = 0; r < 4; ++r) acc[a][b][r] = 0.f;

  for (int ks = 0; ks < 4; ++ks) {
    short8 af[4], bf[4];
    for (int mt = 0; mt < 4; ++mt)
      af[mt] = *(const short8*)&lA[(wm * 64 + mt * 16 + lr) * LD_ + ks * 32 + lg * 8];
    for (int nt = 0; nt < 4; ++nt)
      bf[nt] = *(const short8*)&lB[(wn * 64 + nt * 16 + lr) * LD_ + ks * 32 + lg * 8];
    for (int mt = 0; mt < 4; ++mt)
      for (int nt = 0; nt < 4; ++nt)
        acc[mt][nt] = MFMA16(af[mt], bf[nt], acc[mt][nt]);
  }
  __syncthreads();
  for (int mt = 0; mt < 4; ++mt)          // stage C (bf16) back into lA
    for (int nt = 0; nt < 4; ++nt)
      for (int r = 0; r < 4; ++r)
        lA[(wm * 64 + mt * 16 + lg * 4 + r) * LD_ + wn * 64 + nt * 16 + lr] =
            f2bf(acc[mt][nt][r]);
  __syncthreads();
  for (int idx = tid; idx < 2048; idx += 256) {   // coalesced permuted store
    int r = idx >> 4, c = idx & 15;
    long row = m0 + r;                             // row = (b*S+s)*H + h
    int b = (int)(row >> 15), s = (int)((row >> 3) & 4095), h = (int)(row & 7);
    long g = ((long)(b * 8 + h) * 4096 + s) * 128 + c * 8;
    *(short8*)(out + g) = *(const short8*)&lA[r * LD_ + c * 8];
  }
}

// ---------------------------------------------------------------------------
// Attention v3: block = (b,h,window i), 512 threads = 8 waves, sync-only.
// Keys/values processed in 64-row chunks c in [kc0,kc1) (global 64-row index).
//  - Q fragments in regs. K chunk staged via global_load_lds into a 2x16KB
//    double buffer (XOR granule swizzle, rule #21: pre-swizzled global src +
//    linear LDS dest + swizzled ds_read).  K(c+1) issued right after the top
//    __syncthreads -> latency hidden under QK^T + softmax + V-transpose; it
//    drains at the bottom __syncthreads.
//  - Online softmax per chunk; P kept in regs (packed bf16), PV B-fragment
//    built with 8 __shfl + selects per k-step (all indices compile-time).
//  - V^T built in lV by packed b32 writes (swizzled, conflict-free).
// LDS 48KB, __launch_bounds__(512,4) -> 2 blocks/CU.
// ---------------------------------------------------------------------------
__global__ __launch_bounds__(512, 4) void attn_kernel(
    const unsigned short* __restrict__ qp, const unsigned short* __restrict__ kp,
    const unsigned short* __restrict__ vp, unsigned short* __restrict__ op) {
  __shared__ unsigned short lK[2][64 * 128];   // 2 x 16 KiB
  __shared__ unsigned short lV[128 * 64];      // V^T: 128 d-rows x 64 sk
  const int tid = threadIdx.x;
  const int bid0 = blockIdx.x;
  const int bid = (bid0 & 7) * 256 + (bid0 >> 3);   // XCD swizzle (bijective, 2048=8*256)
  const int b = bid >> 8, h = (bid >> 5) & 7, i = bid & 31;
  const long base = (long)(b * 8 + h) * (4096L * 128);

  const int wv = tid >> 6, L = tid & 63, lr = L & 15, lg = L >> 4;
  const int rsub = L >> 4;                 // staging row-within-4
  const int gsrc = (L & 15) ^ rsub;        // pre-swizzled source granule base

  const int kc0 = (i > 0) ? 2 * i - 2 : 0;           // first 64-row key chunk
  const int kc1 = (i < NW_ - 1) ? 2 * i + 4 : 2 * i + 2;

  // ---- Q fragments in registers (B-operand: col = q-row wv*16+lr) ----
  const unsigned short* qrow = qp + base + (long)i * 16384 + (long)(wv * 16 + lr) * 128;
  short8 bq[4];
#pragma unroll
  for (int ks = 0; ks < 4; ++ks) bq[ks] = *(const short8*)(qrow + ks * 32 + lg * 8);

  // ---- prologue: stage first K chunk into buf 0 ----
  {
    const unsigned short* ksrc = kp + base + (long)kc0 * 8192;
#pragma unroll
    for (int t = 0; t < 2; ++t)
      gload16(ksrc + (long)(wv * 8 + t * 4 + rsub) * 128 + ((gsrc ^ (t << 2)) << 3),
              &lK[0][(wv * 8 + t * 4) * 128]);
  }

  const float csc = 0.08838834764831845f * 1.4426950408889634f;  // scale*log2(e)
  float mm = -3.0e38f, lsum = 0.f;
  float4v Oacc[8];
#pragma unroll
  for (int mt = 0; mt < 8; ++mt)
    for (int r = 0; r < 4; ++r) Oacc[mt][r] = 0.f;

  int cur = 0;
  for (int c = kc0; c < kc1; ++c, cur ^= 1) {
    __syncthreads();   // K_c visible; prev iter's lK[other]/lV reads complete

    // ---- prefetch K(c+1) into other buffer (drains at bottom sync) ----
    if (c + 1 < kc1) {
      const unsigned short* ksrc = kp + base + (long)(c + 1) * 8192;
#pragma unroll
      for (int t = 0; t < 2; ++t)
        gload16(ksrc + (long)(wv * 8 + t * 4 + rsub) * 128 + ((gsrc ^ (t << 2)) << 3),
                &lK[cur ^ 1][(wv * 8 + t * 4) * 128]);
    }

    // ---- V chunk loads (sk pair 2p,2p+1; d block of 8) ----
    const unsigned short* vsrc = vp + base + (long)c * 8192 +
                                 (long)(2 * (L & 31)) * 128 + wv * 16 + ((L >> 5) << 3);
    short8 va = *(const short8*)(vsrc);
    short8 vb = *(const short8*)(vsrc + 128);

    // ---- QK^T: S^T chunk tile, lane owns column sq = wv*16+lr ----
    float4v Sacc[4];
#pragma unroll
    for (int mt = 0; mt < 4; ++mt)
      for (int r = 0; r < 4; ++r) Sacc[mt][r] = 0.f;
#pragma unroll
    for (int ks = 0; ks < 4; ++ks) {
#pragma unroll
      for (int mt = 0; mt < 4; ++mt) {
        short8 ak = *(const short8*)&lK[cur][(mt * 16 + lr) * 128 +
                                            ((((ks << 2) + lg) ^ (lr & 7)) << 3)];
        Sacc[mt] = MFMA16(ak, bq[ks], Sacc[mt]);
      }
    }

    // ---- online softmax update (per q-row: reduce across 4 quads) ----
    float cmax = -3.0e38f;
#pragma unroll
    for (int mt = 0; mt < 4; ++mt)
      for (int r = 0; r < 4; ++r) cmax = fmaxf(cmax, Sacc[mt][r]);
    cmax = fmaxf(cmax, __shfl_xor(cmax, 16));
    cmax = fmaxf(cmax, __shfl_xor(cmax, 32));
    const float mmN = fmaxf(mm, cmax * csc);
    const float f = exp2f(mm - mmN);
    mm = mmN;
    lsum *= f;
#pragma unroll
    for (int mt = 0; mt < 8; ++mt)
      for (int r = 0; r < 4; ++r) Oacc[mt][r] *= f;

    unsigned pk2[8];                       // P packed bf16 pairs per mt
#pragma unroll
    for (int mt = 0; mt < 4; ++mt) {
      float p0 = exp2f(Sacc[mt][0] * csc - mmN);
      float p1 = exp2f(Sacc[mt][1] * csc - mmN);
      float p2 = exp2f(Sacc[mt][2] * csc - mmN);
      float p3 = exp2f(Sacc[mt][3] * csc - mmN);
      lsum += (p0 + p1) + (p2 + p3);
      pk2[2 * mt]     = (unsigned)f2bf(p0) | ((unsigned)f2bf(p1) << 16);
      pk2[2 * mt + 1] = (unsigned)f2bf(p2) | ((unsigned)f2bf(p3) << 16);
    }

    // ---- V^T packed writes (row d, sk-pair p), swizzled, conflict-free ----
    {
      const int p = L & 31;
      const int dbase = wv * 16 + ((L >> 5) << 3);
#pragma unroll
      for (int jj = 0; jj < 8; ++jj) {
        unsigned val = ((unsigned)(unsigned short)va[jj]) |
                       (((unsigned)(unsigned short)vb[jj]) << 16);
        *(unsigned*)((char*)lV + (dbase + jj) * 128 +
                     ((((p >> 2) ^ jj) << 4) | ((p & 3) << 2))) = val;
      }
    }

    __syncthreads();   // V^T visible (also drains K(c+1) gloads — early but safe)

    // ---- PV: O^T += V^T · P^T; B-fragment via shfl (const indices) ----
    const int sel = (lg >> 1) & 1;
    const int srcA = ((lg & 1) << 5) + lr;
#pragma unroll
    for (int ks = 0; ks < 2; ++ks) {
      unsigned u0A = __shfl(pk2[4 * ks + 0], srcA);
      unsigned u1A = __shfl(pk2[4 * ks + 1], srcA);
      unsigned w0A = __shfl(pk2[4 * ks + 2], srcA);
      unsigned w1A = __shfl(pk2[4 * ks + 3], srcA);
      unsigned u0B = __shfl(pk2[4 * ks + 0], srcA + 16);
      unsigned u1B = __shfl(pk2[4 * ks + 1], srcA + 16);
      unsigned w0B = __shfl(pk2[4 * ks + 2], srcA + 16);
      unsigned w1B = __shfl(pk2[4 * ks + 3], srcA + 16);
      uint4v t;
      t[0] = sel ? w0A : u0A;
      t[1] = sel ? w1A : u1A;
      t[2] = sel ? w0B : u0B;
      t[3] = sel ? w1B : u1B;
      short8 bp = __builtin_bit_cast(short8, t);
#pragma unroll
      for (int mt = 0; mt < 8; ++mt) {
        short8 av = *(const short8*)&lV[(mt * 16 + lr) * 64 +
                                        ((((ks << 2) + lg) ^ (lr & 7)) << 3)];
        Oacc[mt] = MFMA16(av, bp, Oacc[mt]);
      }
    }
  }

  lsum += __shfl_xor(lsum, 16);
  lsum += __shfl_xor(lsum, 32);
  const float rl = 1.f / lsum;
  const long obase = base + (long)i * 16384;
#pragma unroll
  for (int mt = 0; mt < 8; ++mt) {         // O^T: 4 consecutive d per lane -> b64
    short4v ok;
    for (int r = 0; r < 4; ++r) ok[r] = (short)f2bf(Oacc[mt][r] * rl);
    *(short4v*)(op + obase + (long)(wv * 16 + lr) * 128 + mt * 16 + lg * 4) = ok;
  }
}

// ---------------------------------------------------------------------------
// Wo fp32 [1024][1024] -> bf16 once (k-plane of ws is dead after attn).
// ---------------------------------------------------------------------------
__global__ __launch_bounds__(256) void cvt_wo(
    const float* __restrict__ w, unsigned short* __restrict__ o) {
  long idx = (long)blockIdx.x * 256 + threadIdx.x;   // 8 elems per thread
  const float* src = w + idx * 8;
  float4v a0 = *(const float4v*)(src);
  float4v a1 = *(const float4v*)(src + 4);
  *(short8*)(o + idx * 8) = pack8(a0, a1);
}

// ---------------------------------------------------------------------------
// out[b*S+s][e] = sum_{h,d} O[b,h,s,d] * Wob[e][h*128+d] + bo[e]   (fp32 out)
// M=32768, N=K=1024; 128x128 tile, BK=64, m97 structure.
// ---------------------------------------------------------------------------
__global__ __launch_bounds__(256) void outproj_kernel(
    const unsigned short* __restrict__ O, const unsigned short* __restrict__ Wob,
    const float* __restrict__ bo, float* __restrict__ out) {
  __shared__ unsigned short lA[128 * 64];   // 16 KiB, linear (gload_lds dest)
  __shared__ unsigned short lB[128 * 64];
  const int tid = threadIdx.x;
  const long m0 = (long)blockIdx.x * 128;
  const int n0 = blockIdx.y * 128;
  const int wv = tid >> 6, L = tid & 63, lr = L & 15, lg = L >> 4;
  const int wm = wv >> 1, wn = wv & 1;

  const int rsub = L >> 3;                  // 0..7
  const int xg = ((L & 7) ^ rsub) * 8;      // pre-swizzled source column (elems)

  const int bb = (int)(m0 >> 12);           // batch (uniform per block)
  const int sbase = (int)(m0 & 4095);
  long Abase[4], Bbase[4];                  // per-lane, hoisted out of K-loop
#pragma unroll
  for (int t = 0; t < 4; ++t) {
    int r = wv * 32 + t * 8 + rsub;
    Abase[t] = (long)bb * 4194304 + (long)(sbase + r) * 128 + xg;  // h=0,d0=0
    Bbase[t] = (long)(n0 + r) * 1024 + xg;
  }

  float4v acc[4][4];
  for (int a = 0; a < 4; ++a)
    for (int b = 0; b < 4; ++b)
      for (int r = 0; r < 4; ++r) acc[a][b][r] = 0.f;

  for (int kk = 0; kk < 1024; kk += 64) {
    const long aoff = ((long)(kk >> 7) << 19) + (kk & 64);  // head stride 2^19
    __syncthreads();                        // previous compute done
#pragma unroll
    for (int t = 0; t < 4; ++t) {
      gload16(O + Abase[t] + aoff, &lA[(wv * 32 + t * 8) * 64]);
      gload16(Wob + Bbase[t] + kk, &lB[(wv * 32 + t * 8) * 64]);
    }
    __syncthreads();                        // vmcnt drained by barrier semantics
#pragma unroll
    for (int ks = 0; ks < 2; ++ks) {
      short8 af[4], bw[4];
      const int gsw = ((ks * 4 + lg) ^ (lr & 7)) << 3;   // swizzled read column
#pragma unroll
      for (int mt = 0; mt < 4; ++mt)
        af[mt] = *(const short8*)&lA[(wm * 64 + mt * 16 + lr) * 64 + gsw];
#pragma unroll
      for (int nt = 0; nt < 4; ++nt)
        bw[nt] = *(const short8*)&lB[(wn * 64 + nt * 16 + lr) * 64 + gsw];
#pragma unroll
      for (int mt = 0; mt < 4; ++mt)
#pragma unroll
        for (int nt = 0; nt < 4; ++nt)
          acc[mt][nt] = MFMA16(af[mt], bw[nt], acc[mt][nt]);
    }
  }

  for (int nt = 0; nt < 4; ++nt) {
    float bv = bo[n0 + wn * 64 + nt * 16 + lr];
    for (int mt = 0; mt < 4; ++mt)
      for (int r = 0; r < 4; ++r)
        out[(m0 + wm * 64 + mt * 16 + lg * 4 + r) * 1024 + n0 + wn * 64 + nt * 16 + lr] =
            acc[mt][nt][r] + bv;
  }
}

// ---------------------------------------------------------------------------
extern "C" void kernel_launch(void* const* d_in, const int* in_sizes, int n_in,
                              void* d_out, int out_size, void* d_ws, size_t ws_size,
                              hipStream_t stream) {
  const float* values = (const float*)d_in[0];
  const float* keys   = (const float*)d_in[1];
  const float* query  = (const float*)d_in[2];
  const float* Wv     = (const float*)d_in[3];
  const float* Wk     = (const float*)d_in[4];
  const float* Wq     = (const float*)d_in[5];
  const float* Wo     = (const float*)d_in[6];
  const float* bo     = (const float*)d_in[7];
  float* out = (float*)d_out;

  const size_t plane = 8UL * 8 * 4096 * 128;      // B*H*S*D = 33554432 elems
  unsigned short* qp = (unsigned short*)d_ws;
  unsigned short* kp = qp + plane;
  unsigned short* vp = kp + plane;

  proj_kernel<<<2048, 256, 0, stream>>>(query, Wq, qp);
  proj_kernel<<<2048, 256, 0, stream>>>(keys, Wk, kp);
  proj_kernel<<<2048, 256, 0, stream>>>(values, Wv, vp);
  attn_kernel<<<2048, 512, 0, stream>>>(qp, kp, vp, qp);     // O overwrites q region
  cvt_wo<<<512, 256, 0, stream>>>(Wo, kp);                   // k-plane dead after attn
  outproj_kernel<<<dim3(256, 8), 256, 0, stream>>>(qp, kp, bo, out);
}